// Round 6
// baseline (148.053 us; speedup 1.0000x reference)
//
#include <hip/hip_runtime.h>
#include <hip/hip_bf16.h>
#include <hip/hip_fp16.h>
#include <math.h>

// Problem constants
#define B_ 4
#define C_ 256
#define H_ 64
#define W_ 64
#define COMP_ 64
#define K2_ 25
#define HW_ (H_*W_)   // 4096
#define EPS_ 1e-5f

typedef float v2f __attribute__((ext_vector_type(2)));
typedef float f32x4 __attribute__((ext_vector_type(4)));
typedef _Float16 half8 __attribute__((ext_vector_type(8)));
#define FMA2(a, b, c) __builtin_elementwise_fma((a), (b), (c))

// ---------------------------------------------------------------------------
// Kernel T: weight layout transforms (unchanged).
// ---------------------------------------------------------------------------
__global__ void k_transpose(const float* __restrict__ w_comp,
                            const float* __restrict__ w_enc,
                            float* __restrict__ wTc,
                            __half* __restrict__ Apack) {
    int t = blockIdx.x * 256 + threadIdx.x;
    if (t < COMP_ * C_) {
        int o = t & 63;
        int c = t >> 6;
        wTc[t] = w_comp[o * C_ + c];
    } else {
        int t2 = t - COMP_ * C_;
        if (t2 < 8 * 18 * 64) {                     // 9216 fragment slots
            int lane = t2 & 63;
            int ks   = (t2 >> 6) % 18;
            int MT   = t2 / (64 * 18);
            int m    = MT * 16 + (lane & 15);
            __half vals[8];
#pragma unroll
            for (int e = 0; e < 8; ++e) {
                int k = ks * 32 + (lane >> 4) * 8 + e;
                int q = k >> 6;                     // 0..8 (ky*3+kx)
                int c = k & 63;
                float wv = (m < 100) ? w_enc[(m * COMP_ + c) * 9 + q] : 0.f;
                vals[e] = __float2half(wv);
            }
            *(float4*)&Apack[(size_t)t2 * 8] = *(float4*)vals;
        }
    }
}

// ---------------------------------------------------------------------------
// Kernel A (v3, unchanged): 1x1 compression + BN + SiLU -> fp16 act16[b][px][c].
// ---------------------------------------------------------------------------
__global__ void __launch_bounds__(512)
k_compress(const float* __restrict__ x, const float* __restrict__ wTc,
           const float* __restrict__ gamma, const float* __restrict__ beta,
           const float* __restrict__ mean, const float* __restrict__ var,
           __half* __restrict__ act16) {
    __shared__ float sx[256 * 68];                 // 69,632 B
    const int tx = threadIdx.x;                    // px
    const int ty = threadIdx.y;                    // og (0..7)
    const int tid = ty * 64 + tx;
    const int ogu = __builtin_amdgcn_readfirstlane(ty);
    const int bb = blockIdx.y;
    const int p0 = blockIdx.x * 64;

    const float* xb = x + (size_t)bb * C_ * HW_ + p0;
#pragma unroll
    for (int l = 0; l < 8; ++l) {
        int e = tid + l * 512;                     // 0..4095
        int c = e >> 4;
        int p4 = (e & 15) << 2;
        float4 v4 = *(const float4*)(xb + (size_t)c * HW_ + p4);
        *(float4*)&sx[c * 68 + p4] = v4;
    }
    __syncthreads();

    v2f acc2[4];
#pragma unroll
    for (int k = 0; k < 4; ++k) acc2[k] = (v2f){0.f, 0.f};

#pragma unroll 8
    for (int c = 0; c < 256; ++c) {
        float xv = sx[c * 68 + tx];
        const v2f* w2 = (const v2f*)(wTc + c * COMP_ + ogu * 8);  // uniform -> s_load
        v2f xv2 = (v2f){xv, xv};
#pragma unroll
        for (int k = 0; k < 4; ++k)
            acc2[k] = FMA2(xv2, w2[k], acc2[k]);
    }

    // BN + SiLU -> fp16, repack to px-major via LDS (stride 68 halfs: 2-way banks)
    __half h8[8];
#pragma unroll
    for (int k = 0; k < 4; ++k) {
#pragma unroll
        for (int h = 0; h < 2; ++h) {
            int o = ty * 8 + 2 * k + h;
            float sv = (h == 0) ? acc2[k].x : acc2[k].y;
            float iv = gamma[o] * rsqrtf(var[o] + EPS_);
            float bn = (sv - mean[o]) * iv + beta[o];
            float sg = 1.f / (1.f + __expf(-bn));
            h8[2 * k + h] = __float2half(bn * sg);
        }
    }
    __syncthreads();                               // sx reads done
    __half* sxh = (__half*)sx;                     // [px][68] halfs
    *(float2*)&sxh[tx * 68 + ty * 8]     = *(float2*)&h8[0];
    *(float2*)&sxh[tx * 68 + ty * 8 + 4] = *(float2*)&h8[4];
    __syncthreads();

    // coalesced copy-out: 512 x 16B, dst fully contiguous 8 KB
    {
        int px = tid >> 3, c8 = tid & 7;
        float2 alo = *(float2*)&sxh[px * 68 + c8 * 8];
        float2 ahi = *(float2*)&sxh[px * 68 + c8 * 8 + 4];
        float4 v = make_float4(alo.x, alo.y, ahi.x, ahi.y);
        __half* ao = act16 + ((size_t)bb * HW_ + p0 + px) * COMP_ + c8 * 8;
        *(float4*)ao = v;
    }
}

// ---------------------------------------------------------------------------
// Kernel B (v4, unchanged): MFMA encoder, j split across grid.
// ---------------------------------------------------------------------------
__global__ void __launch_bounds__(512)
k_encoder(const __half* __restrict__ act16, const __half* __restrict__ Apack,
          __half* __restrict__ maskT) {
    __shared__ __align__(16) __half sact[3 * 34 * 80];   // 16,320 B (160 B/slot)
    __shared__ float cbuf[32 * 129];                      // 16,512 B
    __shared__ __align__(16) __half st[32 * 100];         // 6,400 B
    const int tid = threadIdx.x;
    const int i = blockIdx.x, b = blockIdx.y, jh = blockIdx.z;
    const int lane = tid & 63, w = tid >> 6;

    // ---- stage act rows i-1..i+1, col slots 0..33 (gj = jh*32 + s - 1) ----
    const __half* ab = act16 + (size_t)b * HW_ * COMP_;
    for (int t = tid; t < 3 * 34 * 8; t += 512) {
        int c8 = t & 7;
        int s  = (t >> 3) % 34;
        int r  = t / (34 * 8);
        int gi = i + r - 1;
        int gj = jh * 32 + s - 1;
        float4 v = make_float4(0.f, 0.f, 0.f, 0.f);
        if ((unsigned)gi < 64u && (unsigned)gj < 64u)
            v = *(const float4*)(ab + ((size_t)gi * 64 + gj) * COMP_ + c8 * 8);
        *(float4*)((char*)sact + (size_t)(r * 34 + s) * 160 + c8 * 16) = v;
    }
    __syncthreads();

    // ---- MFMA: 18 k-steps x 2 m-tiles per wave ----
    const int jloc0 = (w & 1) * 16;
    const int MT0   = (w >> 1) * 2;
    const int p = lane & 15, g = lane >> 4;
    f32x4 acc[2];
#pragma unroll
    for (int mt = 0; mt < 2; ++mt) acc[mt] = (f32x4){0.f, 0.f, 0.f, 0.f};
    const half8* Ap = (const half8*)Apack;
#pragma unroll
    for (int ks = 0; ks < 18; ++ks) {
        const int q = ks >> 1, ky = q / 3, kx = q % 3;      // compile-time
        half8 bf = *(const half8*)((const char*)sact +
                       (size_t)(ky * 34 + jloc0 + p + kx) * 160 +
                       ((ks & 1) * 32 + g * 8) * 2);
#pragma unroll
        for (int mt = 0; mt < 2; ++mt) {
            half8 af = Ap[((size_t)(MT0 + mt) * 18 + ks) * 64 + lane];
            acc[mt] = __builtin_amdgcn_mfma_f32_16x16x32_f16(af, bf, acc[mt], 0, 0, 0);
        }
    }

    // ---- C -> LDS transpose buffer [px 0..31][m pad129] ----
#pragma unroll
    for (int mt = 0; mt < 2; ++mt)
#pragma unroll
        for (int r4 = 0; r4 < 4; ++r4)
            cbuf[(jloc0 + p) * 129 + (MT0 + mt) * 16 + g * 4 + r4] = acc[mt][r4];
    __syncthreads();

    // ---- softmax over 25 taps (m = k2*4 + s2), 128 threads ----
    if (tid < 128) {
        int px = tid & 31, s2 = tid >> 5;
        float v[K2_];
        float mx = -1e30f;
#pragma unroll
        for (int k2 = 0; k2 < K2_; ++k2) {
            v[k2] = cbuf[px * 129 + k2 * 4 + s2];
            mx = fmaxf(mx, v[k2]);
        }
        float sum = 0.f;
#pragma unroll
        for (int k2 = 0; k2 < K2_; ++k2) { v[k2] = __expf(v[k2] - mx); sum += v[k2]; }
        float rs = 1.f / sum;
#pragma unroll
        for (int k2 = 0; k2 < K2_; ++k2)
            st[px * 100 + k2 * 4 + s2] = __float2half(v[k2] * rs);
    }
    __syncthreads();

    // ---- coalesced write: 32 px x 100 ch = 400 float4 of halfs ----
    float4* dst = (float4*)(maskT + ((size_t)b * HW_ + i * 64 + jh * 32) * 100);
    const float4* src = (const float4*)st;
    if (tid < 400) dst[tid] = src[tid];
}

// ---------------------------------------------------------------------------
// Kernel C (v5): persistent pipelined reassembly.
// grid 512 blocks (b,i,cc-half; XCD-contiguous id), block 512 thr = 8 waves,
// 2 blocks/CU = 16 waves/CU (was ~8). Per block: stage mask ONCE pre-converted
// to f32 [k2][px][s2] (kills 4 cvts/thread/k2 + 8x restage), then loop 8 cc
// items with register-staged double-buffered x tiles: loads(n+1) issue before
// compute(n), forced vmcnt lands at the ds_write ~700 cyc later (T14).
// One barrier per item. Math bit-identical to the passing v4.1.
// ---------------------------------------------------------------------------
__global__ void __launch_bounds__(512)
k_reassemble(const float* __restrict__ x, const __half* __restrict__ maskT,
             float* __restrict__ out) {
    __shared__ float maskF[K2_ * 256];             // [k2][px][s2] 25.6 KB
    __shared__ float sx[2][5 * 68 * 20];           // 2 x 27.2 KB, [col][16ch+4pad]
    const int tx = threadIdx.x;                    // px / j (lane)
    const int ty = threadIdx.y;                    // ch-pair (0..7)
    const int tid = ty * 64 + tx;

    const int bid = blockIdx.x;                    // 0..511
    const int id  = ((bid & 7) << 6) | (bid >> 3); // XCD gets 64 consecutive ids
    const int half = id & 1;
    const int i    = (id >> 1) & 63;
    const int b    = id >> 7;
    const int cc0  = half * 8;

    // ---- x-gather: issue loads for item cc into vx (decode cached in offs) ----
    float4 vx[3];
    int offs[3];
    auto LOADX = [&](int cc) {
#pragma unroll
        for (int l = 0; l < 3; ++l) {
            int e = tid + l * 512;                 // 0..1535, valid < 1360
            int q = e / 340;
            int rem = e - q * 340;
            int r = rem / 68;
            int col = rem - r * 68;
            int gi = i + r - 2;
            int gj = col - 2;
            offs[l] = (r * 68 + col) * 20 + q * 4;
            float4 v = make_float4(0.f, 0.f, 0.f, 0.f);
            if (e < 1360 && (unsigned)gi < 64u && (unsigned)gj < 64u) {
                const float* p = x + ((size_t)b * C_ + cc * 16 + q * 4) * HW_ + gi * W_ + gj;
                v.x = p[0];
                v.y = p[HW_];
                v.z = p[2 * HW_];
                v.w = p[3 * HW_];
            }
            vx[l] = v;
        }
    };
    auto WRITEX = [&](int d) {
#pragma unroll
        for (int l = 0; l < 3; ++l) {
            int e = tid + l * 512;
            if (e < 1360) *(float4*)&sx[d][offs[l]] = vx[l];
        }
    };

    // ---- prologue: issue x(item0), stage mask (cvt to f32), write x(item0) ----
    LOADX(cc0);
    {
        const __half* mrow = maskT + ((size_t)b * HW_ + i * 64) * 100;
#pragma unroll
        for (int t = 0; t < 4; ++t) {
            int f = tid + t * 512;                 // float-group: 4 halfs each
            if (f < 1600) {
                float2 raw = *(const float2*)(mrow + f * 4);
                __half2 lo = ((const __half2*)&raw)[0];
                __half2 hi = ((const __half2*)&raw)[1];
                float2 flo = __half22float2(lo);
                float2 fhi = __half22float2(hi);
                int px = f / 25, k2 = f - px * 25; // f*4 = px*100 + k2*4 exactly
                *(float4*)&maskF[k2 * 256 + px * 4] =
                    make_float4(flo.x, flo.y, fhi.x, fhi.y);
            }
        }
    }
    WRITEX(0);
    __syncthreads();

    int dbuf = 0;
#pragma unroll 1
    for (int n = 0; n < 8; ++n) {
        const int cc = cc0 + n;
        if (n < 7) LOADX(cc + 1);                  // flies under compute(n)

        const float* sb = sx[dbuf];
        v2f a01[2], a23[2];
#pragma unroll
        for (int cl = 0; cl < 2; ++cl) { a01[cl] = (v2f){0.f, 0.f}; a23[cl] = (v2f){0.f, 0.f}; }

        // prefetch k2=0
        float4 mq = *(const float4*)&maskF[tx * 4];
        float2 xv = *(const float2*)&sb[(0 * 68 + tx + 0) * 20 + ty * 2];
#pragma unroll
        for (int k2 = 0; k2 < K2_; ++k2) {
            float4 mq_c = mq;
            float2 xv_c = xv;
            if (k2 < K2_ - 1) {
                const int kn = k2 + 1;
                const int dy = kn / 5, dx = kn % 5;
                mq = *(const float4*)&maskF[kn * 256 + tx * 4];
                xv = *(const float2*)&sb[(dy * 68 + tx + dx) * 20 + ty * 2];
            }
            v2f m01 = (v2f){mq_c.x, mq_c.y};
            v2f m23 = (v2f){mq_c.z, mq_c.w};
            float xc[2] = {xv_c.x, xv_c.y};
#pragma unroll
            for (int cl = 0; cl < 2; ++cl) {
                v2f xv2 = (v2f){xc[cl], xc[cl]};
                a01[cl] = FMA2(xv2, m01, a01[cl]);
                a23[cl] = FMA2(xv2, m23, a23[cl]);
            }
        }

        if (n < 7) WRITEX(dbuf ^ 1);               // vmcnt lands here (T14)

#pragma unroll
        for (int cl = 0; cl < 2; ++cl) {
            int c = cc * 16 + ty * 2 + cl;
            float* op = out + (((size_t)(b * C_ + c) * 128 + 2 * i) * 128) + 2 * tx;
            *(float2*)op         = float2{a01[cl].x, a01[cl].y};
            *(float2*)(op + 128) = float2{a23[cl].x, a23[cl].y};
        }

        if (n < 7) __syncthreads();                // x(n+1) visible; one barrier/item
        dbuf ^= 1;
    }
}

// ---------------------------------------------------------------------------
extern "C" void kernel_launch(void* const* d_in, const int* in_sizes, int n_in,
                              void* d_out, int out_size, void* d_ws, size_t ws_size,
                              hipStream_t stream) {
    const float* x       = (const float*)d_in[0];
    const float* w_comp  = (const float*)d_in[1];
    const float* bn_g    = (const float*)d_in[2];
    const float* bn_b    = (const float*)d_in[3];
    const float* bn_m    = (const float*)d_in[4];
    const float* bn_v    = (const float*)d_in[5];
    const float* w_enc   = (const float*)d_in[6];
    float* out = (float*)d_out;

    float* ws     = (float*)d_ws;
    float* wTc    = ws;                              // 16,384 floats
    __half* Apack = (__half*)(ws + 16384);           // 73,728 halfs
    __half* act16 = (__half*)(ws + 53248);           // 1,048,576 halfs
    __half* maskT = (__half*)(ws + 577536);          // 1,638,400 halfs

    k_transpose<<<100, 256, 0, stream>>>(w_comp, w_enc, wTc, Apack);
    k_compress<<<dim3(64, B_), dim3(64, 8), 0, stream>>>(x, wTc, bn_g, bn_b, bn_m, bn_v, act16);
    k_encoder<<<dim3(64, B_, 2), 512, 0, stream>>>(act16, Apack, maskT);
    k_reassemble<<<512, dim3(64, 8), 0, stream>>>(x, maskT, out);
}